// Round 1
// baseline (859.500 us; speedup 1.0000x reference)
//
#include <hip/hip_runtime.h>

#define B_TOTAL 65536
#define T_STEPS 28

__device__ __forceinline__ float frcp(float x) { return __builtin_amdgcn_rcpf(x); }
__device__ __forceinline__ float sigf(float x) { return frcp(1.0f + __expf(-x)); }
__device__ __forceinline__ float tanhf_(float x) { return 2.0f * frcp(1.0f + __expf(-2.0f * x)) - 1.0f; }

// ---------------------------------------------------------------------------
// Repack weights into wave-uniform scalar-load-friendly rows in d_ws.
// Row format (132 floats): [b_i b_f b_g b_o][Wi 0..31][Wf 0..31][Wg 0..31][Wo 0..31]
//   enc row k (k=0..3):   inputs = [x(28), he_prev(4)]  -> W*[j<28]=Wih, W*[28+j]=Whh
//   dec row k (rows 4..31): inputs = [hd(28), z(4)]     -> W*[j<28]=Whh, W*[28+j]=Wih
// U rows at float offset 4224, stride 32: [bias][UW 28][pad 3]
// ---------------------------------------------------------------------------
__global__ void repack_kernel(const float* __restrict__ eWih, const float* __restrict__ eWhh,
                              const float* __restrict__ eb,
                              const float* __restrict__ dWih, const float* __restrict__ dWhh,
                              const float* __restrict__ db,
                              const float* __restrict__ UW, const float* __restrict__ Ub,
                              float* __restrict__ w)
{
    const int p = threadIdx.x;
    for (int idx = p; idx < 4 * 132; idx += 256) {
        int k = idx / 132, r = idx % 132;
        float v;
        if (r < 4) v = eb[r * 4 + k];
        else {
            int g = (r - 4) / 32, j = (r - 4) % 32;
            v = (j < 28) ? eWih[(g * 4 + k) * 28 + j] : eWhh[(g * 4 + k) * 4 + (j - 28)];
        }
        w[k * 132 + r] = v;
    }
    for (int idx = p; idx < 28 * 132; idx += 256) {
        int k = idx / 132, r = idx % 132;
        float v;
        if (r < 4) v = db[r * 28 + k];
        else {
            int g = (r - 4) / 32, j = (r - 4) % 32;
            v = (j < 28) ? dWhh[(g * 28 + k) * 28 + j] : dWih[(g * 28 + k) * 4 + (j - 28)];
        }
        w[528 + k * 132 + r] = v;
    }
    for (int idx = p; idx < 10 * 32; idx += 256) {
        int c = idx / 32, r = idx % 32;
        float v = (r == 0) ? Ub[c] : ((r <= 28) ? UW[c * 28 + (r - 1)] : 0.f);
        w[4224 + c * 32 + r] = v;
    }
}

// ---------------------------------------------------------------------------
// Main kernel: block = 256 threads = 4 waves covering 64 elements.
// Wave s: encoder unit s + decoder rows s*7..s*7+6. Weights via uniform
// (scalar) loads from repacked w; h-state exchanged through LDS.
//
// Memory layout changes vs previous version:
//  - x staged per timestep into xBuf[64][29] via block-coalesced dword loads
//    (issued one full timestep ahead; removes 4x redundant scattered loads).
//  - hdBuf is element-major [2][64][29] (stride-29 -> conflict-free for both
//    lane-indexed and (i,k)-indexed access), double-buffered so the out-store
//    pass can read the just-produced h without racing next timestep's writes.
//  - out written via block-coalesced (i,k) mapping: ~4 transactions per wave
//    store instead of 64.
// ---------------------------------------------------------------------------
__global__ __launch_bounds__(256, 4)
void lstm_main(const float* __restrict__ x, const float* __restrict__ w,
               float* __restrict__ out, float* __restrict__ pred)
{
    __shared__ float xBuf[64][29];        // x(t) for the block's 64 elements
    __shared__ float hdBuf[2][64][29];    // decoder h, double-buffered
    __shared__ float heBuf[2][4][64];     // encoder h, double-buffered

    const int tid  = threadIdx.x;
    const int lane = tid & 63;
    const int s    = __builtin_amdgcn_readfirstlane(tid >> 6);
    const int e0   = blockIdx.x * 64;
    const int e    = e0 + lane;

    // staging map: idx = tid + 256*q  ->  (i = idx/28, k = idx%28), 7*256 = 64*28
    int goff[7], loff[7];
#pragma unroll
    for (int q = 0; q < 7; q++) {
        int idx = tid + 256 * q;
        int i = idx / 28;
        int k = idx - 28 * i;
        goff[q] = i * 784 + k;   // element-row offset in x / out
        loff[q] = i * 29 + k;    // flat offset in [64][29] LDS tiles
    }

    const float* __restrict__ xblk = x + (size_t)e0 * 784;
    float* __restrict__ oblk       = out + (size_t)e0 * 784;

    // ---- prologue: zero state, stage x(t=0) ----
    {
        float* hd0 = &hdBuf[0][0][0];
        float* xbf = &xBuf[0][0];
#pragma unroll
        for (int q = 0; q < 7; q++) {
            xbf[loff[q]] = xblk[goff[q]];   // t = 0
            hd0[loff[q]] = 0.f;
        }
        ((float*)heBuf)[tid] = 0.f;         // heBuf[0][*][*]
    }
    __syncthreads();

    const float* __restrict__ wenc = w + s * 132;

    float ce = 0.f;
    float cd[7];
#pragma unroll
    for (int r = 0; r < 7; r++) cd[r] = 0.f;

    for (int t = 0; t < T_STEPS; ++t) {
        const int p = t & 1;

        // ---- phase 1: encoder recurrent input; issue x(t+1) prefetch ----
        float hep[4];
#pragma unroll
        for (int g = 0; g < 4; g++) hep[g] = heBuf[p][g][lane];

        float xr[7];
        if (t < T_STEPS - 1) {
            const int xo = (t + 1) * 28;
#pragma unroll
            for (int q = 0; q < 7; q++) xr[q] = xblk[goff[q] + xo];
        }

        // ---- phase 2: encoder unit s ----
        {
            float xv[28];
#pragma unroll
            for (int j = 0; j < 28; j++) xv[j] = xBuf[lane][j];

            const float* __restrict__ W = wenc + 4;
            float ai = wenc[0], af = wenc[1], ag = wenc[2], ao = wenc[3];
#pragma unroll
            for (int j = 0; j < 28; j++) {
                const float xvj = xv[j];
                ai = fmaf(W[j], xvj, ai);      af = fmaf(W[32 + j], xvj, af);
                ag = fmaf(W[64 + j], xvj, ag); ao = fmaf(W[96 + j], xvj, ao);
            }
#pragma unroll
            for (int j = 0; j < 4; j++) {
                const float hv = hep[j];
                ai = fmaf(W[28 + j], hv, ai); af = fmaf(W[60 + j], hv, af);
                ag = fmaf(W[92 + j], hv, ag); ao = fmaf(W[124 + j], hv, ao);
            }
            ce = sigf(af) * ce + sigf(ai) * tanhf_(ag);
            heBuf[p ^ 1][s][lane] = sigf(ao) * tanhf_(ce);
        }
        __syncthreads();   // barrier A: he exchange complete; xBuf reads done

        // ---- phase 3: decoder inputs ----
        float hz[4];
#pragma unroll
        for (int g = 0; g < 4; g++) hz[g] = heBuf[p ^ 1][g][lane];
        float hd[28];
#pragma unroll
        for (int j = 0; j < 28; j++) hd[j] = hdBuf[p][lane][j];

        // ---- phase 4: decoder rows s*7 .. s*7+6 -> hdBuf[p^1] ----
#pragma unroll
        for (int r = 0; r < 7; r++) {
            const int k = s * 7 + r;
            const float* __restrict__ wrow = w + 528 + k * 132;
            const float* __restrict__ W = wrow + 4;
            float ai = wrow[0], af = wrow[1], ag = wrow[2], ao = wrow[3];
#pragma unroll
            for (int j = 0; j < 28; j++) {
                const float hv = hd[j];
                ai = fmaf(W[j], hv, ai);      af = fmaf(W[32 + j], hv, af);
                ag = fmaf(W[64 + j], hv, ag); ao = fmaf(W[96 + j], hv, ao);
            }
#pragma unroll
            for (int j = 0; j < 4; j++) {
                const float zv = hz[j];
                ai = fmaf(W[28 + j], zv, ai); af = fmaf(W[60 + j], zv, af);
                ag = fmaf(W[92 + j], zv, ag); ao = fmaf(W[124 + j], zv, ao);
            }
            const float cc = sigf(af) * cd[r] + sigf(ai) * tanhf_(ag);
            cd[r] = cc;
            hdBuf[p ^ 1][lane][k] = sigf(ao) * tanhf_(cc);
        }

        // ---- phase 4.5: land x(t+1) into xBuf (reads of xBuf(t) ended at A) ----
        if (t < T_STEPS - 1) {
            float* xbf = &xBuf[0][0];
#pragma unroll
            for (int q = 0; q < 7; q++) xbf[loff[q]] = xr[q];
        }
        __syncthreads();   // barrier B: hdBuf[p^1] + xBuf(t+1) complete

        // ---- phase 5: coalesced out store from hdBuf[p^1] ----
        {
            const float* hsrc = &hdBuf[p ^ 1][0][0];
            const int oo = t * 28;
#pragma unroll
            for (int q = 0; q < 7; q++)
                oblk[goff[q] + oo] = hsrc[loff[q]];
        }
    }

    // ---- final projection + softmax (wave 0 only); last write was hdBuf[0] ----
    if (s == 0) {
        float hf[28];
#pragma unroll
        for (int j = 0; j < 28; j++) hf[j] = hdBuf[0][lane][j];
        float lg[10];
#pragma unroll
        for (int c = 0; c < 10; c++) {
            const float* __restrict__ ur = w + 4224 + c * 32;
            float a = ur[0];
#pragma unroll
            for (int j = 0; j < 28; j++) a = fmaf(ur[1 + j], hf[j], a);
            lg[c] = a;
        }
        float m = lg[0];
#pragma unroll
        for (int c = 1; c < 10; c++) m = fmaxf(m, lg[c]);
        float sum = 0.f;
#pragma unroll
        for (int c = 0; c < 10; c++) { lg[c] = __expf(lg[c] - m); sum += lg[c]; }
        const float inv = frcp(sum);
        float* __restrict__ pr = pred + (size_t)e * 10;
#pragma unroll
        for (int c = 0; c < 10; c++) pr[c] = lg[c] * inv;
    }
}

extern "C" void kernel_launch(void* const* d_in, const int* in_sizes, int n_in,
                              void* d_out, int out_size, void* d_ws, size_t ws_size,
                              hipStream_t stream) {
    const float* x    = (const float*)d_in[0];
    const float* eWih = (const float*)d_in[1];
    const float* eWhh = (const float*)d_in[2];
    const float* eb   = (const float*)d_in[3];
    const float* dWih = (const float*)d_in[4];
    const float* dWhh = (const float*)d_in[5];
    const float* db   = (const float*)d_in[6];
    const float* UW   = (const float*)d_in[7];
    const float* Ub   = (const float*)d_in[8];

    float* w    = (float*)d_ws;                      // 4544 floats used
    float* out  = (float*)d_out;
    float* pred = out + (size_t)B_TOTAL * T_STEPS * 28;

    repack_kernel<<<dim3(1), dim3(256), 0, stream>>>(eWih, eWhh, eb, dWih, dWhh, db, UW, Ub, w);
    lstm_main<<<dim3(B_TOTAL / 64), dim3(256), 0, stream>>>(x, w, out, pred);
}